// Round 1
// 1724.557 us; speedup vs baseline: 1.4433x; 1.4433x over previous
//
#include <hip/hip_runtime.h>
#include <hip/hip_bf16.h>

// Problem constants
#define CUT0 2000
#define CUT1 20000
#define CUT2 50000
#define BSZ  8192
#define HDIM 1024
#define N0MAX 18000   // CUT1-CUT0
#define N1MAX 30000   // CUT2-CUT1
#define HEADW 2002    // CUT0 + 2 tail cols

typedef __attribute__((ext_vector_type(8))) short bf16x8;
typedef __attribute__((ext_vector_type(4))) float f32x4;
typedef __attribute__((ext_vector_type(4))) unsigned short us4;
typedef __attribute__((ext_vector_type(4))) unsigned int u32x4;

__device__ __forceinline__ unsigned short f2bf(float x) {
    // round-to-nearest-even bf16
    unsigned u = __float_as_uint(x);
    unsigned r = u + 0x7fffu + ((u >> 16) & 1u);
    return (unsigned short)(r >> 16);
}

typedef const __attribute__((address_space(1))) void* gas_ptr;
typedef __attribute__((address_space(3))) void* las_ptr;

__device__ __forceinline__ void load_lds16(const void* g, void* l) {
    // 16B per lane, LDS dest = wave-uniform base + lane*16 (m97 pattern)
    __builtin_amdgcn_global_load_lds((gas_ptr)g, (las_ptr)l, 16, 0, 0);
}

// ---------------------------------------------------------------------------
// Build idx0 (2000<=t<20000) and idx1 (t>=20000) in ascending order + counts.
// ---------------------------------------------------------------------------
__global__ __launch_bounds__(1024) void build_idx(const int* __restrict__ targets,
                                                  int* __restrict__ n0,
                                                  int* __restrict__ n1,
                                                  int* __restrict__ idx0,
                                                  int* __restrict__ idx1) {
    __shared__ int s0[1024], s1[1024];
    const int t = threadIdx.x;
    const int base = t * 8;
    int tg[8];
    int c0 = 0, c1 = 0;
#pragma unroll
    for (int i = 0; i < 8; ++i) {
        tg[i] = targets[base + i];
        c0 += (tg[i] >= CUT0 && tg[i] < CUT1) ? 1 : 0;
        c1 += (tg[i] >= CUT1) ? 1 : 0;
    }
    s0[t] = c0; s1[t] = c1;
    __syncthreads();
    for (int off = 1; off < 1024; off <<= 1) {
        int v0 = 0, v1 = 0;
        if (t >= off) { v0 = s0[t - off]; v1 = s1[t - off]; }
        __syncthreads();
        s0[t] += v0; s1[t] += v1;
        __syncthreads();
    }
    int p0 = s0[t] - c0, p1 = s1[t] - c1;   // exclusive prefix
#pragma unroll
    for (int i = 0; i < 8; ++i) {
        if (tg[i] >= CUT0 && tg[i] < CUT1)      idx0[p0++] = base + i;
        else if (tg[i] >= CUT1)                 idx1[p1++] = base + i;
    }
    if (t == 1023) { *n0 = s0[1023]; *n1 = s1[1023]; }
}

// ---------------------------------------------------------------------------
// fp32 -> bf16 (RNE) bulk convert, 8 elems/thread, grid-stride.
// ---------------------------------------------------------------------------
__global__ __launch_bounds__(256) void cvt_bf16(const float* __restrict__ src,
                                                unsigned short* __restrict__ dst,
                                                long long n) {
    long long i = ((long long)blockIdx.x * 256 + threadIdx.x) * 8;
    const long long stride = (long long)gridDim.x * 256 * 8;
    for (; i < n; i += stride) {
        f32x4 a = *(const f32x4*)(src + i);
        f32x4 b = *(const f32x4*)(src + i + 4);
        us4 p = { f2bf(a[0]), f2bf(a[1]), f2bf(a[2]), f2bf(a[3]) };
        us4 q = { f2bf(b[0]), f2bf(b[1]), f2bf(b[2]), f2bf(b[3]) };
        *(us4*)(dst + i)     = p;
        *(us4*)(dst + i + 4) = q;
    }
}

// ---------------------------------------------------------------------------
// head tail columns: out[:, 2000:2002] = hidden @ tail_vec_W^T + tail_vec_b
// ---------------------------------------------------------------------------
__global__ __launch_bounds__(256) void tail_head(const float* __restrict__ hidden,
                                                 const float* __restrict__ tailW,
                                                 const float* __restrict__ tailb,
                                                 float* __restrict__ out) {
    const int wave = threadIdx.x >> 6, lane = threadIdx.x & 63;
    const int row = blockIdx.x * 4 + wave;
    const float* h = hidden + (long long)row * HDIM;
    float s0 = 0.f, s1 = 0.f;
    for (int k = lane; k < HDIM; k += 64) {
        float x = h[k];
        s0 += x * tailW[k];
        s1 += x * tailW[HDIM + k];
    }
#pragma unroll
    for (int off = 32; off; off >>= 1) {
        s0 += __shfl_down(s0, off);
        s1 += __shfl_down(s1, off);
    }
    if (lane == 0) {
        out[(long long)row * HEADW + CUT0]     = s0 + tailb[0];
        out[(long long)row * HEADW + CUT0 + 1] = s1 + tailb[1];
    }
}

// ---------------------------------------------------------------------------
// NEW: bf16 B^T GEMM with global_load_lds staging (m97 structure).
//   C[m,n] = sum_k A[m,k]*B[n,k] (+bias[n])
//   128x128 tile, BK=64, 4 waves (2x2), 64x64/wave, 16x16x32 bf16 MFMA.
//   LDS linear [128][64] bf16 per matrix (global_load_lds requires linear).
//   Row indices CLAMPED to [0, M-1]/[0, N-1]: out-of-tile rows load a
//   duplicate of the last valid row (never OOB); their C rows/cols are
//   skipped in the epilogue, so values are don't-care.
// ---------------------------------------------------------------------------
template<bool GATHER_A, bool OUT_BF16, bool HAS_BIAS>
__global__ __launch_bounds__(256) void gemm_lds(
    const unsigned short* __restrict__ A, const unsigned short* __restrict__ B,
    const int* __restrict__ idxA,
    const int* __restrict__ Mdev, int Mconst,
    int N, int K,
    const float* __restrict__ bias,
    void* __restrict__ Cv,
    long long coff, const int* __restrict__ coffM, long long coffScale,
    int ldC)
{
    const int M = Mdev ? *Mdev : Mconst;
    const int m0 = blockIdx.y * 128;
    const int n0 = blockIdx.x * 128;
    if (m0 >= M) return;

    __shared__ unsigned short As[128 * 64];
    __shared__ unsigned short Bs[128 * 64];

    const int tid  = threadIdx.x;
    const int wave = tid >> 6, lane = tid & 63;
    const int wr = wave >> 1, wc = wave & 1;
    const int lrow = lane & 15;   // fragment row
    const int quad = lane >> 4;   // 0..3

    // staging geometry: each wave-issue covers 8 rows x 64 cols (1 KB);
    // lane l -> row (l>>3), bf16 col (l&7)*8; LDS dest = base + l*16B.
    const int srow = lane >> 3;
    const int scol = (lane & 7) * 8;

    // precompute per-group row base pointers (clamped, gather resolved)
    const unsigned short* aPtr[4];
    const unsigned short* bPtr[4];
#pragma unroll
    for (int g = 0; g < 4; ++g) {
        const int row = (wave * 4 + g) * 8 + srow;   // 0..127
        int am = m0 + row; am = (am < M) ? am : (M - 1);
        long long ar = GATHER_A ? (long long)idxA[am] : (long long)am;
        aPtr[g] = A + ar * (long long)K + scol;
        int bn = n0 + row; bn = (bn < N) ? bn : (N - 1);
        bPtr[g] = B + (long long)bn * K + scol;
    }

    f32x4 acc[4][4];
#pragma unroll
    for (int i = 0; i < 4; ++i)
#pragma unroll
        for (int j = 0; j < 4; ++j) acc[i][j] = (f32x4){0.f, 0.f, 0.f, 0.f};

    const int KT = K >> 6;   // BK = 64
    for (int kt = 0; kt < KT; ++kt) {
        const int kofs = kt << 6;
#pragma unroll
        for (int g = 0; g < 4; ++g) {
            const int grp = wave * 4 + g;
            load_lds16(aPtr[g] + kofs, &As[grp * 8 * 64]);
            load_lds16(bPtr[g] + kofs, &Bs[grp * 8 * 64]);
        }
        __syncthreads();   // compiler drains vmcnt before s_barrier
#pragma unroll
        for (int ks = 0; ks < 2; ++ks) {
            bf16x8 a[4], b[4];
#pragma unroll
            for (int mi = 0; mi < 4; ++mi)
                a[mi] = *(const bf16x8*)&As[(wr * 64 + mi * 16 + lrow) * 64 + ks * 32 + quad * 8];
#pragma unroll
            for (int nj = 0; nj < 4; ++nj)
                b[nj] = *(const bf16x8*)&Bs[(wc * 64 + nj * 16 + lrow) * 64 + ks * 32 + quad * 8];
#pragma unroll
            for (int mi = 0; mi < 4; ++mi)
#pragma unroll
                for (int nj = 0; nj < 4; ++nj)
                    acc[mi][nj] = __builtin_amdgcn_mfma_f32_16x16x32_bf16(
                        a[mi], b[nj], acc[mi][nj], 0, 0, 0);
        }
        __syncthreads();
    }

    // epilogue: C/D layout col=lane&15, row=quad*4+reg  [m89/m91 verified]
    long long cbase = coff + (coffM ? (long long)(*coffM) * coffScale : 0ll);
#pragma unroll
    for (int mi = 0; mi < 4; ++mi) {
#pragma unroll
        for (int v = 0; v < 4; ++v) {
            int m = m0 + wr * 64 + mi * 16 + quad * 4 + v;
            if (m >= M) continue;
#pragma unroll
            for (int nj = 0; nj < 4; ++nj) {
                int n = n0 + wc * 64 + nj * 16 + lrow;
                if (n >= N) continue;
                float r = acc[mi][nj][v];
                if constexpr (OUT_BF16) {
                    ((unsigned short*)Cv)[(long long)m * ldC + n] = f2bf(r);
                } else {
                    if constexpr (HAS_BIAS) r += bias[n];
                    ((float*)Cv)[cbase + (long long)m * ldC + n] = r;
                }
            }
        }
    }
}

// ---------------------------------------------------------------------------
// OLD: unified B^T GEMM (reg-staged, fp32-or-bf16 input) — kept as fallback
// when the workspace is too small for the bf16 pre-convert path.
// ---------------------------------------------------------------------------
template<bool IN_BF16, bool GATHER_A, bool OUT_BF16, bool HAS_BIAS>
__global__ __launch_bounds__(256) void gemm_bt(
    const void* __restrict__ Av, const void* __restrict__ Bv,
    const int* __restrict__ idxA,
    const int* __restrict__ Mdev, int Mconst,
    int N, int K,
    const float* __restrict__ bias,
    void* __restrict__ Cv,
    long long coff, const int* __restrict__ coffM, long long coffScale,
    int ldC)
{
    const int M = Mdev ? *Mdev : Mconst;
    const int m0 = blockIdx.y * 128;
    const int n0 = blockIdx.x * 128;
    if (m0 >= M) return;

    __shared__ unsigned short As[128 * 72];
    __shared__ unsigned short Bs[128 * 72];

    const int tid  = threadIdx.x;
    const int wave = tid >> 6, lane = tid & 63;
    const int wr = wave >> 1, wc = wave & 1;
    const int lrow = lane & 15;
    const int quad = lane >> 4;

    f32x4 acc[4][4];
#pragma unroll
    for (int i = 0; i < 4; ++i)
#pragma unroll
        for (int j = 0; j < 4; ++j) acc[i][j] = (f32x4){0.f, 0.f, 0.f, 0.f};

    const int KT = K >> 6;
    for (int kt = 0; kt < KT; ++kt) {
        if constexpr (IN_BF16) {
            const unsigned short* A  = (const unsigned short*)Av;
            const unsigned short* Bp = (const unsigned short*)Bv;
#pragma unroll
            for (int i = 0; i < 4; ++i) {
                int chunk = tid + i * 256;
                int row = chunk >> 3, kq = chunk & 7;
                int am = m0 + row;
                u32x4 v = {0u, 0u, 0u, 0u};
                if (am < M) {
                    long long r = GATHER_A ? (long long)idxA[am] : (long long)am;
                    v = *(const u32x4*)(A + r * (long long)K + (kt << 6) + (kq << 3));
                }
                *(u32x4*)&As[row * 72 + (kq << 3)] = v;
                int bn = n0 + row;
                u32x4 w = {0u, 0u, 0u, 0u};
                if (bn < N)
                    w = *(const u32x4*)(Bp + (long long)bn * K + (kt << 6) + (kq << 3));
                *(u32x4*)&Bs[row * 72 + (kq << 3)] = w;
            }
        } else {
            const float* A  = (const float*)Av;
            const float* Bp = (const float*)Bv;
#pragma unroll
            for (int i = 0; i < 8; ++i) {
                int chunk = tid + i * 256;
                int row = chunk >> 4, kq = chunk & 15;
                int am = m0 + row;
                f32x4 v = {0.f, 0.f, 0.f, 0.f};
                if (am < M) {
                    long long r = GATHER_A ? (long long)idxA[am] : (long long)am;
                    v = *(const f32x4*)(A + r * (long long)K + (kt << 6) + (kq << 2));
                }
                us4 pv = { f2bf(v[0]), f2bf(v[1]), f2bf(v[2]), f2bf(v[3]) };
                *(us4*)&As[row * 72 + (kq << 2)] = pv;
                int bn = n0 + row;
                f32x4 w = {0.f, 0.f, 0.f, 0.f};
                if (bn < N)
                    w = *(const f32x4*)(Bp + (long long)bn * K + (kt << 6) + (kq << 2));
                us4 pw = { f2bf(w[0]), f2bf(w[1]), f2bf(w[2]), f2bf(w[3]) };
                *(us4*)&Bs[row * 72 + (kq << 2)] = pw;
            }
        }
        __syncthreads();
#pragma unroll
        for (int ks = 0; ks < 2; ++ks) {
            bf16x8 a[4], b[4];
#pragma unroll
            for (int mi = 0; mi < 4; ++mi)
                a[mi] = *(const bf16x8*)&As[(wr * 64 + mi * 16 + lrow) * 72 + ks * 32 + quad * 8];
#pragma unroll
            for (int nj = 0; nj < 4; ++nj)
                b[nj] = *(const bf16x8*)&Bs[(wc * 64 + nj * 16 + lrow) * 72 + ks * 32 + quad * 8];
#pragma unroll
            for (int mi = 0; mi < 4; ++mi)
#pragma unroll
                for (int nj = 0; nj < 4; ++nj)
                    acc[mi][nj] = __builtin_amdgcn_mfma_f32_16x16x32_bf16(
                        a[mi], b[nj], acc[mi][nj], 0, 0, 0);
        }
        __syncthreads();
    }

    long long cbase = coff + (coffM ? (long long)(*coffM) * coffScale : 0ll);
#pragma unroll
    for (int mi = 0; mi < 4; ++mi) {
#pragma unroll
        for (int v = 0; v < 4; ++v) {
            int m = m0 + wr * 64 + mi * 16 + quad * 4 + v;
            if (m >= M) continue;
#pragma unroll
            for (int nj = 0; nj < 4; ++nj) {
                int n = n0 + wc * 64 + nj * 16 + lrow;
                if (n >= N) continue;
                float r = acc[mi][nj][v];
                if constexpr (OUT_BF16) {
                    ((unsigned short*)Cv)[(long long)m * ldC + n] = f2bf(r);
                } else {
                    if constexpr (HAS_BIAS) r += bias[n];
                    ((float*)Cv)[cbase + (long long)m * ldC + n] = r;
                }
            }
        }
    }
}

// ---------------------------------------------------------------------------
extern "C" void kernel_launch(void* const* d_in, const int* in_sizes, int n_in,
                              void* d_out, int out_size, void* d_ws, size_t ws_size,
                              hipStream_t stream) {
    (void)in_sizes; (void)n_in; (void)out_size;
    const float* hidden  = (const float*)d_in[0];
    const float* embed   = (const float*)d_in[1];
    const float* tailW   = (const float*)d_in[2];
    const float* tailb   = (const float*)d_in[3];
    const float* slbias  = (const float*)d_in[4];
    const float* bias0   = (const float*)d_in[5];
    const float* bias1   = (const float*)d_in[6];
    const float* down0   = (const float*)d_in[7];
    const float* down1   = (const float*)d_in[8];
    const int*   targets = (const int*)d_in[9];
    float* out = (float*)d_out;

    // workspace layout
    char* ws = (char*)d_ws;
    int* n0p  = (int*)ws;
    int* n1p  = n0p + 1;
    int* idx0 = (int*)(ws + 256);
    int* idx1 = idx0 + BSZ;
    size_t off = 256 + 2 * (size_t)BSZ * 4;                                    // 65,792
    unsigned short* h0 = (unsigned short*)(ws + off); off += (size_t)BSZ * HDIM * 2;     // 16.8 MB
    unsigned short* h1 = (unsigned short*)(ws + off); off += (size_t)BSZ * 256 * 2;      //  4.2 MB
    unsigned short* e0 = (unsigned short*)(ws + off); off += (size_t)N0MAX * HDIM * 2;   // 36.9 MB
    unsigned short* e1 = (unsigned short*)(ws + off); off += (size_t)N1MAX * 256 * 2;    // 15.4 MB
    // bf16 pre-converted inputs (new path only)
    unsigned short* hbf  = (unsigned short*)(ws + off); off += (size_t)BSZ * HDIM * 2;   // 16.8 MB
    unsigned short* ebf  = (unsigned short*)(ws + off); off += (size_t)CUT2 * HDIM * 2;  // 102.4 MB
    unsigned short* d0bf = (unsigned short*)(ws + off); off += (size_t)HDIM * HDIM * 2;  //  2.1 MB
    unsigned short* d1bf = (unsigned short*)(ws + off); off += (size_t)256 * HDIM * 2;   //  0.5 MB
    const size_t NEED_NEW = off;                                               // ~195.1 MB

    build_idx<<<1, 1024, 0, stream>>>(targets, n0p, n1p, idx0, idx1);

    if (ws_size >= NEED_NEW) {
        // ---- bf16 pre-convert path (global_load_lds GEMMs) ----
        cvt_bf16<<<2048, 256, 0, stream>>>(hidden, hbf, (long long)BSZ * HDIM);
        cvt_bf16<<<2048, 256, 0, stream>>>(embed,  ebf, (long long)CUT2 * HDIM);
        cvt_bf16<<<512,  256, 0, stream>>>(down0, d0bf, (long long)HDIM * HDIM);
        cvt_bf16<<<128,  256, 0, stream>>>(down1, d1bf, (long long)256 * HDIM);

        // head[:, 0:2000] = hidden @ embed[0:2000]^T + shortlist_bias
        gemm_lds<false, false, true><<<dim3(16, 64), 256, 0, stream>>>(
            hbf, ebf, nullptr, nullptr, BSZ, CUT0, HDIM,
            slbias, out, 0ll, nullptr, 0ll, HEADW);

        tail_head<<<BSZ / 4, 256, 0, stream>>>(hidden, tailW, tailb, out);

        // e0 = embed[2000:20000] @ down0^T  -> bf16
        gemm_lds<false, true, false><<<dim3(8, 141), 256, 0, stream>>>(
            ebf + (long long)CUT0 * HDIM, d0bf, nullptr, nullptr, N0MAX, HDIM, HDIM,
            nullptr, e0, 0ll, nullptr, 0ll, HDIM);

        // e1 = embed[20000:50000] @ down1^T -> bf16
        gemm_lds<false, true, false><<<dim3(2, 235), 256, 0, stream>>>(
            ebf + (long long)CUT1 * HDIM, d1bf, nullptr, nullptr, N1MAX, 256, HDIM,
            nullptr, e1, 0ll, nullptr, 0ll, 256);

        // h0 = hidden[idx0] @ down0^T -> bf16
        gemm_lds<true, true, false><<<dim3(8, 64), 256, 0, stream>>>(
            hbf, d0bf, idx0, n0p, 0, HDIM, HDIM,
            nullptr, h0, 0ll, nullptr, 0ll, HDIM);

        // h1 = hidden[idx1] @ down1^T -> bf16
        gemm_lds<true, true, false><<<dim3(2, 64), 256, 0, stream>>>(
            hbf, d1bf, idx1, n1p, 0, 256, HDIM,
            nullptr, h1, 0ll, nullptr, 0ll, 256);

        // out0 = h0 @ e0^T + bias0
        gemm_lds<false, false, true><<<dim3(141, 64), 256, 0, stream>>>(
            h0, e0, nullptr, n0p, 0, N0MAX, HDIM,
            bias0, out, (long long)BSZ * HEADW, nullptr, 0ll, N0MAX);

        // out1 = h1 @ e1^T + bias1
        gemm_lds<false, false, true><<<dim3(235, 64), 256, 0, stream>>>(
            h1, e1, nullptr, n1p, 0, N1MAX, 256,
            bias1, out, (long long)BSZ * HEADW, n0p, (long long)N0MAX, N1MAX);
    } else {
        // ---- fallback: previous verified path (fp32 reg-staged) ----
        gemm_bt<false, false, false, true><<<dim3(16, 64), 256, 0, stream>>>(
            hidden, embed, nullptr, nullptr, BSZ, CUT0, HDIM,
            slbias, out, 0ll, nullptr, 0ll, HEADW);

        tail_head<<<BSZ / 4, 256, 0, stream>>>(hidden, tailW, tailb, out);

        gemm_bt<false, false, true, false><<<dim3(8, 141), 256, 0, stream>>>(
            embed + (long long)CUT0 * HDIM, down0, nullptr, nullptr, N0MAX, HDIM, HDIM,
            nullptr, e0, 0ll, nullptr, 0ll, HDIM);

        gemm_bt<false, false, true, false><<<dim3(2, 235), 256, 0, stream>>>(
            embed + (long long)CUT1 * HDIM, down1, nullptr, nullptr, N1MAX, 256, HDIM,
            nullptr, e1, 0ll, nullptr, 0ll, 256);

        gemm_bt<false, true, true, false><<<dim3(8, 64), 256, 0, stream>>>(
            hidden, down0, idx0, n0p, 0, HDIM, HDIM,
            nullptr, h0, 0ll, nullptr, 0ll, HDIM);

        gemm_bt<false, true, true, false><<<dim3(2, 64), 256, 0, stream>>>(
            hidden, down1, idx1, n1p, 0, 256, HDIM,
            nullptr, h1, 0ll, nullptr, 0ll, 256);

        gemm_bt<true, false, false, true><<<dim3(141, 64), 256, 0, stream>>>(
            h0, e0, nullptr, n0p, 0, N0MAX, HDIM,
            bias0, out, (long long)BSZ * HEADW, nullptr, 0ll, N0MAX);

        gemm_bt<true, false, false, true><<<dim3(235, 64), 256, 0, stream>>>(
            h1, e1, nullptr, n1p, 0, N1MAX, 256,
            bias1, out, (long long)BSZ * HEADW, n0p, (long long)N0MAX, N1MAX);
    }
}

// Round 2
// 1667.152 us; speedup vs baseline: 1.4929x; 1.0344x over previous
//
#include <hip/hip_runtime.h>
#include <hip/hip_bf16.h>

// Problem constants
#define CUT0 2000
#define CUT1 20000
#define CUT2 50000
#define BSZ  8192
#define HDIM 1024
#define N0MAX 18000   // CUT1-CUT0
#define N1MAX 30000   // CUT2-CUT1
#define HEADW 2002    // CUT0 + 2 tail cols

typedef __attribute__((ext_vector_type(8))) short bf16x8;
typedef __attribute__((ext_vector_type(4))) float f32x4;
typedef __attribute__((ext_vector_type(4))) unsigned short us4;

__device__ __forceinline__ unsigned short f2bf(float x) {
    // round-to-nearest-even bf16
    unsigned u = __float_as_uint(x);
    unsigned r = u + 0x7fffu + ((u >> 16) & 1u);
    return (unsigned short)(r >> 16);
}

typedef const __attribute__((address_space(1))) void* gas_ptr;
typedef __attribute__((address_space(3))) void* las_ptr;

__device__ __forceinline__ void load_lds16(const void* g, void* l) {
    // 16B per lane, LDS dest = wave-uniform base + lane*16 (m97 pattern)
    __builtin_amdgcn_global_load_lds((gas_ptr)g, (las_ptr)l, 16, 0, 0);
}

// ---------------------------------------------------------------------------
// Build idx0 (2000<=t<20000) and idx1 (t>=20000) in ascending order + counts.
// ---------------------------------------------------------------------------
__global__ __launch_bounds__(1024) void build_idx(const int* __restrict__ targets,
                                                  int* __restrict__ n0,
                                                  int* __restrict__ n1,
                                                  int* __restrict__ idx0,
                                                  int* __restrict__ idx1) {
    __shared__ int s0[1024], s1[1024];
    const int t = threadIdx.x;
    const int base = t * 8;
    int tg[8];
    int c0 = 0, c1 = 0;
#pragma unroll
    for (int i = 0; i < 8; ++i) {
        tg[i] = targets[base + i];
        c0 += (tg[i] >= CUT0 && tg[i] < CUT1) ? 1 : 0;
        c1 += (tg[i] >= CUT1) ? 1 : 0;
    }
    s0[t] = c0; s1[t] = c1;
    __syncthreads();
    for (int off = 1; off < 1024; off <<= 1) {
        int v0 = 0, v1 = 0;
        if (t >= off) { v0 = s0[t - off]; v1 = s1[t - off]; }
        __syncthreads();
        s0[t] += v0; s1[t] += v1;
        __syncthreads();
    }
    int p0 = s0[t] - c0, p1 = s1[t] - c1;   // exclusive prefix
#pragma unroll
    for (int i = 0; i < 8; ++i) {
        if (tg[i] >= CUT0 && tg[i] < CUT1)      idx0[p0++] = base + i;
        else if (tg[i] >= CUT1)                 idx1[p1++] = base + i;
    }
    if (t == 1023) { *n0 = s0[1023]; *n1 = s1[1023]; }
}

// ---------------------------------------------------------------------------
// fp32 -> bf16 (RNE) bulk convert, 8 elems/thread, grid-stride.
// ---------------------------------------------------------------------------
__global__ __launch_bounds__(256) void cvt_bf16(const float* __restrict__ src,
                                                unsigned short* __restrict__ dst,
                                                long long n) {
    long long i = ((long long)blockIdx.x * 256 + threadIdx.x) * 8;
    const long long stride = (long long)gridDim.x * 256 * 8;
    for (; i < n; i += stride) {
        f32x4 a = *(const f32x4*)(src + i);
        f32x4 b = *(const f32x4*)(src + i + 4);
        us4 p = { f2bf(a[0]), f2bf(a[1]), f2bf(a[2]), f2bf(a[3]) };
        us4 q = { f2bf(b[0]), f2bf(b[1]), f2bf(b[2]), f2bf(b[3]) };
        *(us4*)(dst + i)     = p;
        *(us4*)(dst + i + 4) = q;
    }
}

// ---------------------------------------------------------------------------
// head tail columns: out[:, 2000:2002] = hidden @ tail_vec_W^T + tail_vec_b
// ---------------------------------------------------------------------------
__global__ __launch_bounds__(256) void tail_head(const float* __restrict__ hidden,
                                                 const float* __restrict__ tailW,
                                                 const float* __restrict__ tailb,
                                                 float* __restrict__ out) {
    const int wave = threadIdx.x >> 6, lane = threadIdx.x & 63;
    const int row = blockIdx.x * 4 + wave;
    const float* h = hidden + (long long)row * HDIM;
    float s0 = 0.f, s1 = 0.f;
    for (int k = lane; k < HDIM; k += 64) {
        float x = h[k];
        s0 += x * tailW[k];
        s1 += x * tailW[HDIM + k];
    }
#pragma unroll
    for (int off = 32; off; off >>= 1) {
        s0 += __shfl_down(s0, off);
        s1 += __shfl_down(s1, off);
    }
    if (lane == 0) {
        out[(long long)row * HEADW + CUT0]     = s0 + tailb[0];
        out[(long long)row * HEADW + CUT0 + 1] = s1 + tailb[1];
    }
}

// ---------------------------------------------------------------------------
// gemm256: C[m,n] = sum_k A[m,k]*B[n,k] (+bias[n]), bf16 inputs.
//   256x256 tile, BK=32, 512 threads = 8 waves (2M x 4N), 128x64 per wave,
//   16x16x32 bf16 MFMA, acc[8][4].
//   LDS: ring-4 of K-tiles (As/Bs 4 x [256][32] bf16 = 128 KiB total),
//   3 tiles prefetched ahead via global_load_lds; counted s_waitcnt vmcnt(12)
//   (never 0 in steady state); raw s_barrier (no __syncthreads vmcnt drain).
//   Ring safety: tile t+4 reuses slot (t&3), issued at top of iter t+1,
//   strictly after the end-barrier of iter t (where slot t&3 was last read).
//   T2 swizzle: LDS col-slot s holds global col-slot s^(row&3) (8-elem units);
//   achieved by pre-swizzling the per-lane GLOBAL source (linear LDS dest,
//   rule #21) and XOR-ing the ds_read address. 2-way banks (free).
//   A-row map: SPLIT_GATHER ? (r<gsplit ? gbase+r : idxTail[r-gsplit]) : r.
//   Rows clamped to M-1/N-1 (don't-care values, epilogue guards).
// ---------------------------------------------------------------------------
template<bool SPLIT_GATHER, bool OUT_BF16, bool HAS_BIAS>
__global__ __launch_bounds__(512) void gemm256(
    const unsigned short* __restrict__ A, const unsigned short* __restrict__ B,
    int gsplit, int gbase, const int* __restrict__ idxTail,
    int Mbase, const int* __restrict__ Mdev,
    int N, int K,
    const float* __restrict__ bias,
    void* __restrict__ Cv,
    long long coff, const int* __restrict__ coffM, long long coffScale,
    int ldC)
{
    const int M = Mbase + (Mdev ? *Mdev : 0);
    const int m0 = blockIdx.y * 256;
    const int n0 = blockIdx.x * 256;
    if (m0 >= M) return;

    __shared__ unsigned short As[4][8192];   // [slot][256 rows x 32 cols]
    __shared__ unsigned short Bs[4][8192];

    const int tid  = threadIdx.x;
    const int wave = tid >> 6, lane = tid & 63;
    const int wr = wave >> 2;        // 0..1  (M)
    const int wc = wave & 3;         // 0..3  (N)
    const int lrow = lane & 15;      // fragment row
    const int quad = lane >> 4;      // 0..3  (k-slot of fragment)

    // ---- staging geometry: wave covers tile rows [wave*32, wave*32+32),
    //      two 16-row chunks; lane l -> row chunk*16 + (l>>2),
    //      global col-slot pre-swizzled: 8*((l&3) ^ ((l>>2)&3)).
    const int srow = lane >> 2;                             // 0..15
    const int scol = (((lane & 3) ^ (srow & 3)) << 3);      // elems

    int tr0 = wave * 32 + srow;          // chunk 0 tile row
    int tr1 = tr0 + 16;                  // chunk 1 tile row

    int am0 = m0 + tr0; am0 = am0 < M ? am0 : M - 1;
    int am1 = m0 + tr1; am1 = am1 < M ? am1 : M - 1;
    long long ar0, ar1;
    if constexpr (SPLIT_GATHER) {
        ar0 = (am0 < gsplit) ? (long long)(gbase + am0) : (long long)idxTail[am0 - gsplit];
        ar1 = (am1 < gsplit) ? (long long)(gbase + am1) : (long long)idxTail[am1 - gsplit];
    } else {
        ar0 = am0; ar1 = am1;
    }
    const unsigned short* aP0 = A + ar0 * (long long)K + scol;
    const unsigned short* aP1 = A + ar1 * (long long)K + scol;

    int bn0 = n0 + tr0; bn0 = bn0 < N ? bn0 : N - 1;
    int bn1 = n0 + tr1; bn1 = bn1 < N ? bn1 : N - 1;
    const unsigned short* bP0 = B + (long long)bn0 * K + scol;
    const unsigned short* bP1 = B + (long long)bn1 * K + scol;

    f32x4 acc[8][4];
#pragma unroll
    for (int i = 0; i < 8; ++i)
#pragma unroll
        for (int j = 0; j < 4; ++j) acc[i][j] = (f32x4){0.f, 0.f, 0.f, 0.f};

    const int KT = K >> 5;   // BK = 32

    auto issue = [&](int tt) {
        const int st = tt & 3;
        const int kofs = tt << 5;
        unsigned short* as = &As[st][wave * 1024];
        unsigned short* bs = &Bs[st][wave * 1024];
        load_lds16(aP0 + kofs, as);
        load_lds16(aP1 + kofs, as + 512);
        load_lds16(bP0 + kofs, bs);
        load_lds16(bP1 + kofs, bs + 512);
    };

    // prologue: 3 tiles in flight
    const int npro = KT < 3 ? KT : 3;
    for (int tt = 0; tt < npro; ++tt) issue(tt);

    // per-lane-constant read swizzle: col-slot quad ^ (R&3), R&3 == lrow&3
    const int rdswz = ((quad ^ (lrow & 3)) << 3);           // elems

    for (int t = 0; t < KT; ++t) {
        const int tt = t + 3;
        if (tt < KT) issue(tt);

        int infl = KT - 1 - t; if (infl > 3) infl = 3;      // tiles beyond t in flight
        if (infl >= 3)      asm volatile("s_waitcnt vmcnt(12)" ::: "memory");
        else if (infl == 2) asm volatile("s_waitcnt vmcnt(8)"  ::: "memory");
        else if (infl == 1) asm volatile("s_waitcnt vmcnt(4)"  ::: "memory");
        else                asm volatile("s_waitcnt vmcnt(0)"  ::: "memory");

        __builtin_amdgcn_s_barrier();
        asm volatile("" ::: "memory");   // keep ds_reads below the barrier

        const unsigned short* Asl = &As[t & 3][0];
        const unsigned short* Bsl = &Bs[t & 3][0];

        bf16x8 a[8], b[4];
#pragma unroll
        for (int mi = 0; mi < 8; ++mi) {
            const int R = wr * 128 + mi * 16 + lrow;
            a[mi] = *(const bf16x8*)&Asl[R * 32 + rdswz];
        }
#pragma unroll
        for (int nj = 0; nj < 4; ++nj) {
            const int R = wc * 64 + nj * 16 + lrow;
            b[nj] = *(const bf16x8*)&Bsl[R * 32 + rdswz];
        }

        __builtin_amdgcn_s_setprio(1);
#pragma unroll
        for (int mi = 0; mi < 8; ++mi)
#pragma unroll
            for (int nj = 0; nj < 4; ++nj)
                acc[mi][nj] = __builtin_amdgcn_mfma_f32_16x16x32_bf16(
                    a[mi], b[nj], acc[mi][nj], 0, 0, 0);
        __builtin_amdgcn_s_setprio(0);

        asm volatile("" ::: "memory");   // keep ds_reads above the end barrier
        __builtin_amdgcn_s_barrier();    // slot t&3 free for tile t+4 next iter
    }

    // epilogue: C/D layout col=lane&15, row=quad*4+reg  [m89/m91 verified]
    long long cbase = coff + (coffM ? (long long)(*coffM) * coffScale : 0ll);
#pragma unroll
    for (int mi = 0; mi < 8; ++mi) {
#pragma unroll
        for (int v = 0; v < 4; ++v) {
            int m = m0 + wr * 128 + mi * 16 + quad * 4 + v;
            if (m >= M) continue;
#pragma unroll
            for (int nj = 0; nj < 4; ++nj) {
                int n = n0 + wc * 64 + nj * 16 + lrow;
                if (n >= N) continue;
                float r = acc[mi][nj][v];
                if constexpr (OUT_BF16) {
                    ((unsigned short*)Cv)[(long long)m * ldC + n] = f2bf(r);
                } else {
                    if constexpr (HAS_BIAS) r += bias[n];
                    ((float*)Cv)[cbase + (long long)m * ldC + n] = r;
                }
            }
        }
    }
}

// ---------------------------------------------------------------------------
extern "C" void kernel_launch(void* const* d_in, const int* in_sizes, int n_in,
                              void* d_out, int out_size, void* d_ws, size_t ws_size,
                              hipStream_t stream) {
    (void)in_sizes; (void)n_in; (void)out_size; (void)ws_size;
    const float* hidden  = (const float*)d_in[0];
    const float* embed   = (const float*)d_in[1];
    const float* tailW   = (const float*)d_in[2];
    const float* tailb   = (const float*)d_in[3];
    const float* slbias  = (const float*)d_in[4];
    const float* bias0   = (const float*)d_in[5];
    const float* bias1   = (const float*)d_in[6];
    const float* down0   = (const float*)d_in[7];
    const float* down1   = (const float*)d_in[8];
    const int*   targets = (const int*)d_in[9];
    float* out = (float*)d_out;

    // workspace layout (~195.06 MB, <= 195.13 MB proven available in R1)
    char* ws = (char*)d_ws;
    int* n0p  = (int*)ws;
    int* n1p  = n0p + 1;
    int* idx0 = (int*)(ws + 256);
    int* idx1 = idx0 + BSZ;
    size_t off = 256 + 2 * (size_t)BSZ * 4;                                     // 65,792
    // ubf: [hidden (8192 rows); embed (50000 rows)] bf16, row stride 1024
    unsigned short* ubf  = (unsigned short*)(ws + off);
    off += (size_t)(BSZ + CUT2) * HDIM * 2;                                     // 119.18 MB
    // c0: [e0 (18000 rows); h0 (<=8192 rows)] bf16, ld 1024
    unsigned short* c0   = (unsigned short*)(ws + off);
    off += (size_t)(N0MAX + BSZ) * HDIM * 2;                                    // 53.64 MB
    // c1: [e1 (30000 rows); h1 (<=8192 rows)] bf16, ld 256
    unsigned short* c1   = (unsigned short*)(ws + off);
    off += (size_t)(N1MAX + BSZ) * 256 * 2;                                     // 19.55 MB
    unsigned short* d0bf = (unsigned short*)(ws + off); off += (size_t)HDIM * HDIM * 2;
    unsigned short* d1bf = (unsigned short*)(ws + off); off += (size_t)256 * HDIM * 2;

    const unsigned short* ebf = ubf + (size_t)BSZ * HDIM;   // embed part, row v = ubf row 8192+v

    build_idx<<<1, 1024, 0, stream>>>(targets, n0p, n1p, idx0, idx1);

    // bf16 pre-convert
    cvt_bf16<<<2048, 256, 0, stream>>>(hidden, ubf, (long long)BSZ * HDIM);
    cvt_bf16<<<2048, 256, 0, stream>>>(embed,  (unsigned short*)ebf, (long long)CUT2 * HDIM);
    cvt_bf16<<<512,  256, 0, stream>>>(down0, d0bf, (long long)HDIM * HDIM);
    cvt_bf16<<<128,  256, 0, stream>>>(down1, d1bf, (long long)256 * HDIM);

    // head[:, 0:2000] = hidden @ embed[0:2000]^T + shortlist_bias
    gemm256<false, false, true><<<dim3(8, 32), 512, 0, stream>>>(
        ubf, ebf, 0, 0, nullptr,
        BSZ, nullptr, CUT0, HDIM,
        slbias, out, 0ll, nullptr, 0ll, HEADW);

    // head[:, 2000:2002]
    tail_head<<<BSZ / 4, 256, 0, stream>>>(hidden, tailW, tailb, out);

    // c0 = [embed[2000:20000]; hidden[idx0]] @ down0^T -> bf16 (merged e0+h0)
    // A-row r: r<18000 -> ubf row 8192+2000+r ; else ubf row idx0[r-18000]
    gemm256<true, true, false><<<dim3(4, 103), 512, 0, stream>>>(
        ubf, d0bf, N0MAX, BSZ + CUT0, idx0,
        N0MAX, n0p, HDIM, HDIM,
        nullptr, c0, 0ll, nullptr, 0ll, HDIM);

    // c1 = [embed[20000:50000]; hidden[idx1]] @ down1^T -> bf16 (merged e1+h1)
    gemm256<true, true, false><<<dim3(1, 150), 512, 0, stream>>>(
        ubf, d1bf, N1MAX, BSZ + CUT1, idx1,
        N1MAX, n1p, 256, HDIM,
        nullptr, c1, 0ll, nullptr, 0ll, 256);

    // out0 = h0-part @ e0-part^T + bias0  (fp32 into d_out after head)
    gemm256<false, false, true><<<dim3(71, 32), 512, 0, stream>>>(
        c0 + (size_t)N0MAX * HDIM, c0, 0, 0, nullptr,
        0, n0p, N0MAX, HDIM,
        bias0, out, (long long)BSZ * HEADW, nullptr, 0ll, N0MAX);

    // out1 = h1-part @ e1-part^T + bias1  (fp32 after out0; offset uses n0)
    gemm256<false, false, true><<<dim3(118, 32), 512, 0, stream>>>(
        c1 + (size_t)N1MAX * 256, c1, 0, 0, nullptr,
        0, n1p, N1MAX, 256,
        bias1, out, (long long)BSZ * HEADW, n0p, (long long)N0MAX, N1MAX);
}